// Round 9
// baseline (988.589 us; speedup 1.0000x reference)
//
#include <hip/hip_runtime.h>
#include <math.h>

// VQ-VAE forward. All Cin=256 convs on bf16 MFMA implicit GEMM.
// R9: BK=64 K-loop (half the barriers, 2x MFMA per stage), all-bf16
// activation/residual chain (relu fused into 3x3 LDS staging).

typedef unsigned short ushort;
typedef short bf16x8 __attribute__((ext_vector_type(8)));
typedef float f32x4 __attribute__((ext_vector_type(4)));

__device__ __forceinline__ ushort f2bf(float f) {
    unsigned u = __builtin_bit_cast(unsigned, f);
    unsigned r = (u + 0x7fffu + ((u >> 16) & 1u)) >> 16;
    return (ushort)r;
}
__device__ __forceinline__ float bfl(unsigned u) { return __builtin_bit_cast(float, u << 16); }
__device__ __forceinline__ float bfh(unsigned u) { return __builtin_bit_cast(float, u & 0xffff0000u); }

// packed bf16 relu: zero each 16-bit half whose sign bit is set (5 ops/uint)
__device__ __forceinline__ unsigned relu_u(unsigned u) {
    unsigned m = (u >> 15) & 0x00010001u;
    return u & ~((m << 16) - m);
}
__device__ __forceinline__ uint4 relu4(uint4 v) {
    v.x = relu_u(v.x); v.y = relu_u(v.y); v.z = relu_u(v.z); v.w = relu_u(v.w);
    return v;
}

// ======================= weight packing =======================
// MFMA layout (per layer): [cls][tap][cb(8)][co(256)][k(32)] bf16.

__global__ void k_pack_c3x4(const float* __restrict__ w0, const float* __restrict__ w1,
                            const float* __restrict__ w2, const float* __restrict__ w3,
                            ushort* __restrict__ o0, ushort* __restrict__ o1,
                            ushort* __restrict__ o2, ushort* __restrict__ o3) {
    int layer = blockIdx.x / 2304;
    int i = (blockIdx.x - layer * 2304) * 256 + threadIdx.x;     // 589824
    const float* w = layer == 0 ? w0 : layer == 1 ? w1 : layer == 2 ? w2 : w3;
    ushort* o = layer == 0 ? o0 : layer == 1 ? o1 : layer == 2 ? o2 : o3;
    int kk = i & 31, co = (i >> 5) & 255, cb = (i >> 13) & 7, t = i >> 16;
    int ci = cb * 32 + kk, kh = t / 3, kw = t % 3;
    o[i] = f2bf(w[((co * 256 + ci) * 3 + kh) * 3 + kw]);
}

__global__ void k_pack_c1x1x4(const float* __restrict__ w0, const float* __restrict__ w1,
                              const float* __restrict__ w2, const float* __restrict__ w3,
                              ushort* __restrict__ o0, ushort* __restrict__ o1,
                              ushort* __restrict__ o2, ushort* __restrict__ o3) {
    int layer = blockIdx.x >> 8;
    int i = (blockIdx.x & 255) * 256 + threadIdx.x;              // 65536
    const float* w = layer == 0 ? w0 : layer == 1 ? w1 : layer == 2 ? w2 : w3;
    ushort* o = layer == 0 ? o0 : layer == 1 ? o1 : layer == 2 ? o2 : o3;
    int kk = i & 31, co = (i >> 5) & 255, cb = (i >> 13) & 7;
    o[i] = f2bf(w[co * 256 + cb * 32 + kk]);
}

__global__ void k_pack_c2dc1(const float* __restrict__ wc2, const float* __restrict__ wdc1,
                             ushort* __restrict__ oc2, ushort* __restrict__ odc1) {
    int g = blockIdx.x;
    int layer = g >> 12;
    int i = (g & 4095) * 256 + threadIdx.x;                      // 1048576
    int kk = i & 31, co = (i >> 5) & 255, cb = (i >> 13) & 7;
    int t = (i >> 16) & 3, cls = i >> 18;
    int a = t >> 1, b = t & 1, ci = cb * 32 + kk;
    if (layer == 0) {
        int ph = cls >> 1, pw = cls & 1;
        int kh = ph ? 2 * a : 2 * a + 1;
        int kw = pw ? 2 * b : 2 * b + 1;
        oc2[i] = f2bf(wc2[((co * 256 + ci) * 4 + kh) * 4 + kw]);
    } else {
        int py = cls >> 1, px = cls & 1;
        int kh0 = (py + 1) & 1, kw0 = (px + 1) & 1;
        odc1[i] = f2bf(wdc1[((ci * 256 + co) * 4 + kh0 + 2 * a) * 4 + kw0 + 2 * b]);
    }
}

__global__ void k_pack_c1f(const float* __restrict__ w, float* __restrict__ o) {
    int i = blockIdx.x * 256 + threadIdx.x;           // 12288
    int co = i & 255, k = i >> 8;
    int ci = k >> 4, kh = (k >> 2) & 3, kw = k & 3;
    o[k * 256 + co] = w[((co * 3 + ci) * 4 + kh) * 4 + kw];
}

// deconv2 MFMA weights: [tap(9)][cb(8)][oc(16)][k(32)] bf16
__global__ void k_pack_dc2m(const float* __restrict__ w, ushort* __restrict__ o) {
    int i = blockIdx.x * 256 + threadIdx.x;           // 36864
    int kk = i & 31, oc = (i >> 5) & 15, cb = (i >> 9) & 7, t = i >> 12;
    int dy = t / 3 - 1, dx = t % 3 - 1;
    int ci = cb * 32 + kk;
    float v = 0.f;
    if (oc < 12) {
        int cls = oc / 3, co = oc - cls * 3;
        int py = cls >> 1, px = cls & 1;
        int kh = 1 + py - 2 * dy, kw = 1 + px - 2 * dx;
        if ((unsigned)kh < 4u && (unsigned)kw < 4u)
            v = w[((ci * 3 + co) * 4 + kh) * 4 + kw];
    }
    o[i] = f2bf(v);
}

// VQ codebook prepack: apk [tile(16)][kstep(2)][lane(64)][8] bf16 ; en [256] fp32
__global__ void k_pack_vq(const float* __restrict__ cb, ushort* __restrict__ apk,
                          float* __restrict__ en) {
    if (blockIdx.x < 64) {
        int i = blockIdx.x * 256 + threadIdx.x;
        int j = i & 7, lane = (i >> 3) & 63, s = (i >> 9) & 1, t = i >> 10;
        int code = t * 16 + (lane & 15);
        int dim = s * 32 + (lane >> 4) * 8 + j;
        apk[i] = f2bf(cb[code * 64 + dim]);
    } else {
        int code = threadIdx.x;
        float s = 0.f;
        for (int d = 0; d < 64; ++d) { float v = cb[code * 64 + d]; s += v * v; }
        en[code] = s;
    }
}

// ======================= conv1: 3->256 k4 s2, 128->64, LDS-staged =======================
__global__ __launch_bounds__(256) void k_conv1n(const float* __restrict__ x,
                                                const float* __restrict__ wt,   // [48][256] f32
                                                const float* __restrict__ bias,
                                                ushort* __restrict__ o) {       // NHWC64 bf16
    __shared__ float sx[12][132];
    int b = blockIdx.x;                  // 32n * 64h
    int h = b & 63, n = b >> 6;
    int tid = threadIdx.x;
    for (int c = tid; c < 12 * 128; c += 256) {
        int t = c >> 7, wi = c & 127;
        int ci = t >> 2, kh = t & 3;
        int hi = 2 * h - 1 + kh;
        float v = ((unsigned)hi < 128u) ? x[((long)n * 3 + ci) * 16384 + hi * 128 + wi] : 0.f;
        sx[t][wi + 1] = v;
    }
    if (tid < 24) { int t = tid >> 1; sx[t][(tid & 1) ? 129 : 0] = 0.f; }
    int co = tid;
    float wr[48];
#pragma unroll
    for (int k = 0; k < 48; ++k) wr[k] = wt[k * 256 + co];
    float bco = bias[co];
    __syncthreads();
    ushort* op = o + (((long)n * 64 + h) * 64) * 256 + co;
    for (int w = 0; w < 64; ++w) {
        float acc = bco;
#pragma unroll
        for (int t = 0; t < 12; ++t) {
            const float* xr = &sx[t][2 * w];
            acc += xr[0] * wr[t * 4] + xr[1] * wr[t * 4 + 1]
                 + xr[2] * wr[t * 4 + 2] + xr[3] * wr[t * 4 + 3];
        }
        op[w * 256] = f2bf(acc);
    }
}

// ======================= unified MFMA conv, BK=64 =======================
// MODE 0: 3x3 pad1 (9 taps), 32x32 NHWC  (RELU_STAGE applies relu on load)
// MODE 1: 1x1
// MODE 2: conv2 4x4 s2 (4 phases x 4 taps), in 64x64 NHWC, out 32x32
// MODE 3: deconv1 per-parity (4 taps), in 32x32 NHWC, out 64x64 NHWC
// Block: 128 threads = 2 waves. Block tile 64co x 128m. Wave tile 64co x 64m.
// LDS: [row(6)][q(8)][col(34)][8 ushorts], conflict-free both sides. 26112 B.
#define SX64(r, qq, c) (((((r) << 3) + (qq)) * 34 + (c)) << 3)

template <int MODE, bool HAS_BIAS, bool ADD_RES, bool RELU_STAGE, bool RELU_OUT>
__global__ __launch_bounds__(128, 2) void k_mconv(const ushort* __restrict__ xin,
                                                  const ushort* __restrict__ wpk,
                                                  const float* __restrict__ bias,
                                                  const ushort* __restrict__ res,
                                                  ushort* __restrict__ obf) {
    constexpr int NT = (MODE == 0) ? 9 : ((MODE == 1) ? 1 : 4);
    constexpr int NITER = (MODE == 2) ? 16 : 4;
    constexpr int NR = (MODE == 1) ? 4 : 6;

    __shared__ __align__(16) ushort sX[6 * 8 * 34 * 8];   // 26112 B

    int tid = threadIdx.x;
    int lane = tid & 63, wv = tid >> 6;               // 2 waves
    int q4 = lane >> 4, l15 = lane & 15;
    int b = blockIdx.x;
    int mblk = b & 7, coslab = (b >> 3) & 3;
    int cls = (MODE == 3) ? ((b >> 5) & 3) : 0;
    int n = (MODE == 3) ? (b >> 7) : (b >> 5);
    int h0 = mblk * 4;

    // zero col pads c=0,33 for all (r,q): 96 cells
    if (tid < 96) {
        int r = tid / 16, rem = tid & 15, qq = rem >> 1, cc = (rem & 1) ? 33 : 0;
        uint4 z; z.x = z.y = z.z = z.w = 0;
        *(uint4*)&sX[SX64(r, qq, cc)] = z;
    }

    int qsel = tid & 3;
    int wst = (tid >> 2) & 31;

    int bbase[4];
#pragma unroll
    for (int bt = 0; bt < 4; ++bt) {
        int mloc = wv * 64 + bt * 16 + l15;           // 0..127
        int ro = mloc >> 5, col = mloc & 31;
        bbase[bt] = SX64(ro + 1, q4, col + 1);
    }

    f32x4 acc[4][4];
#pragma unroll
    for (int at = 0; at < 4; ++at)
#pragma unroll
        for (int bt = 0; bt < 4; ++bt) acc[at][bt] = 0.f;

    uint4 sreg[NR][2];
    auto stage_load = [&](int it2) {
        int cbp2 = (MODE == 2) ? (it2 >> 2) : it2;
        int ph2 = (MODE == 2) ? (it2 & 3) : 0;
        int ph_h2 = ph2 >> 1, ph_w2 = ph2 & 1;
#pragma unroll
        for (int r = 0; r < NR; ++r) {
            int rr = (MODE == 1) ? r + 1 : r;
            int hh = h0 + rr - 1;
            bool valid = (unsigned)hh < 32u;
#pragma unroll
            for (int j = 0; j < 2; ++j) {
                int cio = cbp2 * 64 + j * 32 + qsel * 8;
                long off2;
                if (MODE == 2)
                    off2 = (((long)n * 64 + 2 * hh + ph_h2) * 64 + (2 * wst + ph_w2)) * 256 + cio;
                else
                    off2 = (((long)n * 32 + hh) * 32 + wst) * 256 + cio;
                uint4 v;
                if (valid) {
                    v = *(const uint4*)(xin + off2);
                    if (RELU_STAGE) v = relu4(v);
                } else { v.x = 0; v.y = 0; v.z = 0; v.w = 0; }
                sreg[r][j] = v;
            }
        }
    };
    stage_load(0);

    for (int it = 0; it < NITER; ++it) {
        int cbp = (MODE == 2) ? (it >> 2) : it;
        int ph = (MODE == 2) ? (it & 3) : 0;
        int ph_h = ph >> 1, ph_w = ph & 1;
        int clsi = (MODE == 2) ? ph : cls;

        __syncthreads();                 // previous taps' LDS reads done
#pragma unroll
        for (int r = 0; r < NR; ++r) {
            int rr = (MODE == 1) ? r + 1 : r;
#pragma unroll
            for (int j = 0; j < 2; ++j)
                *(uint4*)&sX[SX64(rr, j * 4 + qsel, wst + 1)] = sreg[r][j];
        }
        if (it + 1 < NITER) stage_load(it + 1);   // prefetch, loads stay in flight
        __syncthreads();                 // staging visible

#pragma unroll
        for (int t = 0; t < NT; ++t) {
            int dy, dx;
            if (MODE == 0) { dy = t / 3 - 1; dx = t % 3 - 1; }
            else if (MODE == 1) { dy = 0; dx = 0; }
            else if (MODE == 2) { dy = (t >> 1) - ph_h; dx = (t & 1) - ph_w; }
            else { dy = (cls >> 1) - (t >> 1); dx = (cls & 1) - (t & 1); }
            int doff = (dy * 272 + dx) * 8;          // 272 = 8*34

#pragma unroll
            for (int j = 0; j < 2; ++j) {
                const ushort* wpj = wpk +
                    ((((long)(clsi * NT + t)) * 8 + (cbp * 2 + j)) * 256 + coslab * 64 + l15) * 32 + q4 * 8;
                bf16x8 af[4];
#pragma unroll
                for (int at = 0; at < 4; ++at) af[at] = *(const bf16x8*)(wpj + at * 512);
                bf16x8 bfr[4];
#pragma unroll
                for (int bt = 0; bt < 4; ++bt)
                    bfr[bt] = *(const bf16x8*)&sX[bbase[bt] + j * 1088 + doff];  // 1088 = 4*34*8
#pragma unroll
                for (int at = 0; at < 4; ++at)
#pragma unroll
                    for (int bt = 0; bt < 4; ++bt)
                        acc[at][bt] = __builtin_amdgcn_mfma_f32_16x16x32_bf16(af[at], bfr[bt],
                                                                              acc[at][bt], 0, 0, 0);
            }
        }
    }

    // ---- epilogue (all-bf16) ----
    int co_base = coslab * 64;
#pragma unroll
    for (int at = 0; at < 4; ++at) {
        int co_t = co_base + at * 16 + q4 * 4;
        float bv[4] = {0.f, 0.f, 0.f, 0.f};
        if (HAS_BIAS) {
            float4 b4 = *(const float4*)(bias + co_t);
            bv[0] = b4.x; bv[1] = b4.y; bv[2] = b4.z; bv[3] = b4.w;
        }
#pragma unroll
        for (int bt = 0; bt < 4; ++bt) {
            int m = mblk * 128 + wv * 64 + bt * 16 + l15;
            long oaddr;
            if (MODE == 3) {
                int oy = m >> 5, ox = m & 31;
                int py = cls >> 1, px = cls & 1;
                oaddr = (((long)n * 64 + 2 * oy + py) * 64 + 2 * ox + px) * 256 + co_t;
            } else {
                oaddr = ((long)n * 1024 + m) * 256 + co_t;
            }
            float v[4];
#pragma unroll
            for (int r = 0; r < 4; ++r) v[r] = acc[at][bt][r] + bv[r];
            if (ADD_RES) {
                uint2 rr = *(const uint2*)(res + oaddr);
                v[0] += bfl(rr.x); v[1] += bfh(rr.x);
                v[2] += bfl(rr.y); v[3] += bfh(rr.y);
            }
            if (RELU_OUT) {
#pragma unroll
                for (int r = 0; r < 4; ++r) v[r] = fmaxf(v[r], 0.f);
            }
            uint2 pk;
            pk.x = (unsigned)f2bf(v[0]) | ((unsigned)f2bf(v[1]) << 16);
            pk.y = (unsigned)f2bf(v[2]) | ((unsigned)f2bf(v[3]) << 16);
            *(uint2*)(obf + oaddr) = pk;
        }
    }
}

// ======================= VQ via MFMA (bf16 out only) =======================
__global__ __launch_bounds__(256) void k_vq2(const ushort* __restrict__ zb,
                                             const ushort* __restrict__ apk,  // [16][2][64][8]
                                             const float* __restrict__ en,    // [256]
                                             const float* __restrict__ cbf,   // [256][64] fp32
                                             ushort* __restrict__ vqb,        // bf16 NHWC (no relu)
                                             float* __restrict__ loss) {
    __shared__ int sIdx[64];
    __shared__ float sLoss[64];
    int tid = threadIdx.x, lane = tid & 63, wv = tid >> 6;
    int q = lane >> 4, l15 = lane & 15;
    int r0 = blockIdx.x * 64;
    int R = r0 + wv * 16;

    const ushort* zp = zb + ((long)(R + l15)) * 64 + q * 8;
    bf16x8 b0 = *(const bf16x8*)zp;
    bf16x8 b1 = *(const bf16x8*)(zp + 32);

    float z2 = 0.f;
    {
        const unsigned* u0 = (const unsigned*)&b0;
        const unsigned* u1 = (const unsigned*)&b1;
#pragma unroll
        for (int i = 0; i < 4; ++i) {
            float a = bfl(u0[i]), bb = bfh(u0[i]);
            float c = bfl(u1[i]), d = bfh(u1[i]);
            z2 += a * a + bb * bb + c * c + d * d;
        }
    }

    float best = 3.4e38f;
    int bidx = 0;
#pragma unroll
    for (int t = 0; t < 16; ++t) {
        bf16x8 a0 = *(const bf16x8*)(apk + ((t * 2 + 0) * 64 + lane) * 8);
        bf16x8 a1 = *(const bf16x8*)(apk + ((t * 2 + 1) * 64 + lane) * 8);
        f32x4 acc = {0.f, 0.f, 0.f, 0.f};
        acc = __builtin_amdgcn_mfma_f32_16x16x32_bf16(a0, b0, acc, 0, 0, 0);
        acc = __builtin_amdgcn_mfma_f32_16x16x32_bf16(a1, b1, acc, 0, 0, 0);
        float4 e4 = *(const float4*)(en + t * 16 + q * 4);
        float sc[4] = {e4.x - 2.f * acc[0], e4.y - 2.f * acc[1],
                       e4.z - 2.f * acc[2], e4.w - 2.f * acc[3]};
#pragma unroll
        for (int r = 0; r < 4; ++r) {
            int code = t * 16 + q * 4 + r;
            if (sc[r] < best) { best = sc[r]; bidx = code; }
        }
    }
#pragma unroll
    for (int m = 16; m <= 32; m <<= 1) {
        float ob = __shfl_xor(best, m);
        int oi = __shfl_xor(bidx, m);
        if (ob < best || (ob == best && oi < bidx)) { best = ob; bidx = oi; }
        z2 += __shfl_xor(z2, m);
    }
    if (q == 0) {
        sIdx[wv * 16 + l15] = bidx;
        sLoss[wv * 16 + l15] = best + z2;
    }
    __syncthreads();

    if (wv == 0) {
        float l = sLoss[lane];
#pragma unroll
        for (int m = 1; m < 64; m <<= 1) l += __shfl_xor(l, m);
        if (lane == 0) atomicAdd(loss, l * (1.25f / 8388608.f));
    }

    unsigned* vb = (unsigned*)(vqb + (long)r0 * 64);
#pragma unroll
    for (int k = 0; k < 8; ++k) {
        int i = k * 256 + tid;           // 0..2047 uints
        int rl = i >> 5, jp = i & 31;
        int idx = sIdx[rl];
        float v0 = cbf[idx * 64 + 2 * jp];
        float v1 = cbf[idx * 64 + 2 * jp + 1];
        vb[i] = (unsigned)f2bf(v0) | ((unsigned)f2bf(v1) << 16);
    }
}

// ======================= deconv2 via MFMA, BK=64: 256->3, 64->128, tanh =========
#define SD64(r, qq, c) (((((r) << 3) + (qq)) * 66 + (c)) << 3)

__global__ __launch_bounds__(256, 2) void k_deconv2m(const ushort* __restrict__ xin,
                                                     const ushort* __restrict__ wpk, // [9][8][16][32]
                                                     const float* __restrict__ bias,
                                                     float* __restrict__ o) {
    __shared__ __align__(16) ushort sX[6 * 8 * 66 * 8];   // 50688 B

    int tid = threadIdx.x, lane = tid & 63, wv = tid >> 6;
    int q4 = lane >> 4, l15 = lane & 15;
    int b = blockIdx.x;                   // 32n * 16mt = 512
    int mt = b & 15, n = b >> 4;
    int h0 = mt * 4;

    if (tid < 96) {
        int r = tid / 16, rem = tid & 15, qq = rem >> 1, cc = (rem & 1) ? 65 : 0;
        uint4 z; z.x = z.y = z.z = z.w = 0;
        *(uint4*)&sX[SD64(r, qq, cc)] = z;
    }

    int qsel = tid & 3, wst = (tid >> 2) & 63;

    int bbase[4];
#pragma unroll
    for (int bt = 0; bt < 4; ++bt) {
        int mloc = wv * 64 + bt * 16 + l15;       // 0..255
        int ro = mloc >> 6, col = mloc & 63;
        bbase[bt] = SD64(ro + 1, q4, col + 1);
    }

    f32x4 acc[4];
#pragma unroll
    for (int bt = 0; bt < 4; ++bt) acc[bt] = 0.f;

    uint4 sreg[6][2];
    auto stage_load = [&](int cbp2) {
#pragma unroll
        for (int r = 0; r < 6; ++r) {
            int hh = h0 + r - 1;
            bool valid = (unsigned)hh < 64u;
#pragma unroll
            for (int j = 0; j < 2; ++j) {
                uint4 v;
                if (valid)
                    v = *(const uint4*)(xin + (((long)n * 64 + hh) * 64 + wst) * 256
                                        + cbp2 * 64 + j * 32 + qsel * 8);
                else { v.x = 0; v.y = 0; v.z = 0; v.w = 0; }
                sreg[r][j] = v;
            }
        }
    };
    stage_load(0);

    for (int cbp = 0; cbp < 4; ++cbp) {
        __syncthreads();
#pragma unroll
        for (int r = 0; r < 6; ++r)
#pragma unroll
            for (int j = 0; j < 2; ++j)
                *(uint4*)&sX[SD64(r, j * 4 + qsel, wst + 1)] = sreg[r][j];
        if (cbp < 3) stage_load(cbp + 1);
        __syncthreads();

#pragma unroll
        for (int t = 0; t < 9; ++t) {
            int dy = t / 3 - 1, dx = t % 3 - 1;
            int doff = (dy * 528 + dx) * 8;          // 528 = 8*66
#pragma unroll
            for (int j = 0; j < 2; ++j) {
                bf16x8 af = *(const bf16x8*)(wpk + (((t * 8 + cbp * 2 + j) * 16 + l15) * 32 + q4 * 8));
#pragma unroll
                for (int bt = 0; bt < 4; ++bt) {
                    bf16x8 bf = *(const bf16x8*)&sX[bbase[bt] + j * 2112 + doff];  // 2112 = 4*66*8
                    acc[bt] = __builtin_amdgcn_mfma_f32_16x16x32_bf16(af, bf, acc[bt], 0, 0, 0);
                }
            }
        }
    }

    if (q4 < 3) {
#pragma unroll
        for (int bt = 0; bt < 4; ++bt) {
            int mloc = wv * 64 + bt * 16 + l15;
            int u = h0 + (mloc >> 6), v = mloc & 63;
#pragma unroll
            for (int r = 0; r < 4; ++r) {
                int oc = q4 * 4 + r;
                int cls = oc / 3, cs = oc - cls * 3;
                int py = cls >> 1, px = cls & 1;
                o[(((long)n * 3 + cs) * 128 + 2 * u + py) * 128 + 2 * v + px] =
                    tanhf(acc[bt][r] + bias[cs]);
            }
        }
    }
}

// ======================= launcher =======================
extern "C" void kernel_launch(void* const* d_in, const int* in_sizes, int n_in,
                              void* d_out, int out_size, void* d_ws, size_t ws_size,
                              hipStream_t stream) {
    (void)in_sizes; (void)n_in; (void)out_size; (void)ws_size;
    const float* x        = (const float*)d_in[0];
    const float* enc_w1   = (const float*)d_in[1];
    const float* enc_b1   = (const float*)d_in[2];
    const float* enc_w2   = (const float*)d_in[3];
    const float* enc_b2   = (const float*)d_in[4];
    const float* er1_w3   = (const float*)d_in[5];
    const float* er1_w1   = (const float*)d_in[6];
    const float* er2_w3   = (const float*)d_in[7];
    const float* er2_w1   = (const float*)d_in[8];
    const float* codebook = (const float*)d_in[9];
    const float* dr1_w3   = (const float*)d_in[10];
    const float* dr1_w1   = (const float*)d_in[11];
    const float* dr2_w3   = (const float*)d_in[12];
    const float* dr2_w1   = (const float*)d_in[13];
    const float* dt1_w    = (const float*)d_in[14];
    const float* dt1_b    = (const float*)d_in[15];
    const float* dt2_w    = (const float*)d_in[16];
    const float* dt2_b    = (const float*)d_in[17];

    float* recon = (float*)d_out;
    float* loss  = recon + 1572864;

    char* ws = (char*)d_ws;
    size_t off = 0;
    auto alloc = [&](size_t bytes) { char* p = ws + off; off += (bytes + 255) & ~(size_t)255; return p; };
    ushort* N64  = (ushort*)alloc(67108864);   // [32,64,64,256] bf16
    ushort* X0   = (ushort*)alloc(16777216);   // bf16 NHWC 32x32 tensors
    ushort* X1   = (ushort*)alloc(16777216);
    ushort* X2   = (ushort*)alloc(16777216);
    ushort* X3   = (ushort*)alloc(16777216);
    ushort* X4   = (ushort*)alloc(16777216);
    ushort* wpk_c2   = (ushort*)alloc(2097152);
    ushort* wpk_dc1  = (ushort*)alloc(2097152);
    ushort* wpk_er13 = (ushort*)alloc(1179648);
    ushort* wpk_er23 = (ushort*)alloc(1179648);
    ushort* wpk_dr13 = (ushort*)alloc(1179648);
    ushort* wpk_dr23 = (ushort*)alloc(1179648);
    ushort* wpk_er11 = (ushort*)alloc(131072);
    ushort* wpk_er21 = (ushort*)alloc(131072);
    ushort* wpk_dr11 = (ushort*)alloc(131072);
    ushort* wpk_dr21 = (ushort*)alloc(131072);
    float*  wt_c1    = (float*)alloc(49152);
    ushort* w2pk     = (ushort*)alloc(73728);
    ushort* apk      = (ushort*)alloc(32768);
    float*  en       = (float*)alloc(1024);

    hipMemsetAsync(loss, 0, sizeof(float), stream);

    // weight packing
    k_pack_c1f<<<48, 256, 0, stream>>>(enc_w1, wt_c1);
    k_pack_c2dc1<<<8192, 256, 0, stream>>>(enc_w2, dt1_w, wpk_c2, wpk_dc1);
    k_pack_c3x4<<<9216, 256, 0, stream>>>(er1_w3, er2_w3, dr1_w3, dr2_w3,
                                          wpk_er13, wpk_er23, wpk_dr13, wpk_dr23);
    k_pack_c1x1x4<<<1024, 256, 0, stream>>>(er1_w1, er2_w1, dr1_w1, dr2_w1,
                                            wpk_er11, wpk_er21, wpk_dr11, wpk_dr21);
    k_pack_dc2m<<<144, 256, 0, stream>>>(dt2_w, w2pk);
    k_pack_vq<<<65, 256, 0, stream>>>(codebook, apk, en);

    // encoder
    k_conv1n<<<2048, 256, 0, stream>>>(x, wt_c1, enc_b1, N64);
    // conv2: N64 -> X0 (z2, no relu)
    k_mconv<2, true, false, false, false><<<1024, 128, 0, stream>>>(N64, wpk_c2, enc_b2, nullptr, X0);
    // er1: 3x3(relu-stage) X0 -> X1(relu'd) ; 1x1 X1 + res X0 -> X2
    k_mconv<0, false, false, true, true><<<1024, 128, 0, stream>>>(X0, wpk_er13, nullptr, nullptr, X1);
    k_mconv<1, false, true, false, false><<<1024, 128, 0, stream>>>(X1, wpk_er11, nullptr, X0, X2);
    // er2: X2 -> X1 ; X1 + res X2 -> X3 (z, VQ input)
    k_mconv<0, false, false, true, true><<<1024, 128, 0, stream>>>(X2, wpk_er23, nullptr, nullptr, X1);
    k_mconv<1, false, true, false, false><<<1024, 128, 0, stream>>>(X1, wpk_er21, nullptr, X2, X3);
    // VQ: X3 -> X4 (vq, no relu) + loss
    k_vq2<<<2048, 256, 0, stream>>>(X3, apk, en, codebook, X4, loss);
    // dr1: X4 -> X1 ; X1 + res X4 -> X0
    k_mconv<0, false, false, true, true><<<1024, 128, 0, stream>>>(X4, wpk_dr13, nullptr, nullptr, X1);
    k_mconv<1, false, true, false, false><<<1024, 128, 0, stream>>>(X1, wpk_dr11, nullptr, X4, X0);
    // dr2: X0 -> X1 ; X1 + res X0 -> X2
    k_mconv<0, false, false, true, true><<<1024, 128, 0, stream>>>(X0, wpk_dr23, nullptr, nullptr, X1);
    k_mconv<1, false, true, false, false><<<1024, 128, 0, stream>>>(X1, wpk_dr21, nullptr, X0, X2);
    // deconv1: X2 -> N64
    k_mconv<3, true, false, false, false><<<4096, 128, 0, stream>>>(X2, wpk_dc1, dt1_b, nullptr, N64);
    // deconv2 + tanh
    k_deconv2m<<<512, 256, 0, stream>>>(N64, w2pk, dt2_b, recon);
}

// Round 10
// 849.715 us; speedup vs baseline: 1.1634x; 1.1634x over previous
//
#include <hip/hip_runtime.h>
#include <math.h>

// VQ-VAE forward. All Cin=256 convs on bf16 MFMA implicit GEMM.
// R10 = R8 structure (BK=32, 2-wave blocks, A-frag preload, staging prefetch)
//       + all-bf16 activation/residual chain (R9's only validated win).

typedef unsigned short ushort;
typedef short bf16x8 __attribute__((ext_vector_type(8)));
typedef float f32x4 __attribute__((ext_vector_type(4)));

__device__ __forceinline__ ushort f2bf(float f) {
    unsigned u = __builtin_bit_cast(unsigned, f);
    unsigned r = (u + 0x7fffu + ((u >> 16) & 1u)) >> 16;
    return (ushort)r;
}
__device__ __forceinline__ float bfl(unsigned u) { return __builtin_bit_cast(float, u << 16); }
__device__ __forceinline__ float bfh(unsigned u) { return __builtin_bit_cast(float, u & 0xffff0000u); }

// packed bf16 relu: zero each 16-bit half whose sign bit is set
__device__ __forceinline__ unsigned relu_u(unsigned u) {
    unsigned m = (u >> 15) & 0x00010001u;
    return u & ~((m << 16) - m);
}
__device__ __forceinline__ uint4 relu4(uint4 v) {
    v.x = relu_u(v.x); v.y = relu_u(v.y); v.z = relu_u(v.z); v.w = relu_u(v.w);
    return v;
}

// ======================= weight packing =======================
// MFMA layout (per layer): [cls][tap][cb(8)][co(256)][k(32)] bf16.

__global__ void k_pack_c3x4(const float* __restrict__ w0, const float* __restrict__ w1,
                            const float* __restrict__ w2, const float* __restrict__ w3,
                            ushort* __restrict__ o0, ushort* __restrict__ o1,
                            ushort* __restrict__ o2, ushort* __restrict__ o3) {
    int layer = blockIdx.x / 2304;
    int i = (blockIdx.x - layer * 2304) * 256 + threadIdx.x;     // 589824
    const float* w = layer == 0 ? w0 : layer == 1 ? w1 : layer == 2 ? w2 : w3;
    ushort* o = layer == 0 ? o0 : layer == 1 ? o1 : layer == 2 ? o2 : o3;
    int kk = i & 31, co = (i >> 5) & 255, cb = (i >> 13) & 7, t = i >> 16;
    int ci = cb * 32 + kk, kh = t / 3, kw = t % 3;
    o[i] = f2bf(w[((co * 256 + ci) * 3 + kh) * 3 + kw]);
}

__global__ void k_pack_c1x1x4(const float* __restrict__ w0, const float* __restrict__ w1,
                              const float* __restrict__ w2, const float* __restrict__ w3,
                              ushort* __restrict__ o0, ushort* __restrict__ o1,
                              ushort* __restrict__ o2, ushort* __restrict__ o3) {
    int layer = blockIdx.x >> 8;
    int i = (blockIdx.x & 255) * 256 + threadIdx.x;              // 65536
    const float* w = layer == 0 ? w0 : layer == 1 ? w1 : layer == 2 ? w2 : w3;
    ushort* o = layer == 0 ? o0 : layer == 1 ? o1 : layer == 2 ? o2 : o3;
    int kk = i & 31, co = (i >> 5) & 255, cb = (i >> 13) & 7;
    o[i] = f2bf(w[co * 256 + cb * 32 + kk]);
}

__global__ void k_pack_c2dc1(const float* __restrict__ wc2, const float* __restrict__ wdc1,
                             ushort* __restrict__ oc2, ushort* __restrict__ odc1) {
    int g = blockIdx.x;
    int layer = g >> 12;
    int i = (g & 4095) * 256 + threadIdx.x;                      // 1048576
    int kk = i & 31, co = (i >> 5) & 255, cb = (i >> 13) & 7;
    int t = (i >> 16) & 3, cls = i >> 18;
    int a = t >> 1, b = t & 1, ci = cb * 32 + kk;
    if (layer == 0) {
        int ph = cls >> 1, pw = cls & 1;
        int kh = ph ? 2 * a : 2 * a + 1;
        int kw = pw ? 2 * b : 2 * b + 1;
        oc2[i] = f2bf(wc2[((co * 256 + ci) * 4 + kh) * 4 + kw]);
    } else {
        int py = cls >> 1, px = cls & 1;
        int kh0 = (py + 1) & 1, kw0 = (px + 1) & 1;
        odc1[i] = f2bf(wdc1[((ci * 256 + co) * 4 + kh0 + 2 * a) * 4 + kw0 + 2 * b]);
    }
}

__global__ void k_pack_c1f(const float* __restrict__ w, float* __restrict__ o) {
    int i = blockIdx.x * 256 + threadIdx.x;           // 12288
    int co = i & 255, k = i >> 8;
    int ci = k >> 4, kh = (k >> 2) & 3, kw = k & 3;
    o[k * 256 + co] = w[((co * 3 + ci) * 4 + kh) * 4 + kw];
}

// deconv2 MFMA weights: [tap(9)][cb(8)][oc(16)][k(32)] bf16
__global__ void k_pack_dc2m(const float* __restrict__ w, ushort* __restrict__ o) {
    int i = blockIdx.x * 256 + threadIdx.x;           // 36864
    int kk = i & 31, oc = (i >> 5) & 15, cb = (i >> 9) & 7, t = i >> 12;
    int dy = t / 3 - 1, dx = t % 3 - 1;
    int ci = cb * 32 + kk;
    float v = 0.f;
    if (oc < 12) {
        int cls = oc / 3, co = oc - cls * 3;
        int py = cls >> 1, px = cls & 1;
        int kh = 1 + py - 2 * dy, kw = 1 + px - 2 * dx;
        if ((unsigned)kh < 4u && (unsigned)kw < 4u)
            v = w[((ci * 3 + co) * 4 + kh) * 4 + kw];
    }
    o[i] = f2bf(v);
}

// VQ codebook prepack: apk [tile(16)][kstep(2)][lane(64)][8] bf16 ; en [256] fp32
__global__ void k_pack_vq(const float* __restrict__ cb, ushort* __restrict__ apk,
                          float* __restrict__ en) {
    if (blockIdx.x < 64) {
        int i = blockIdx.x * 256 + threadIdx.x;
        int j = i & 7, lane = (i >> 3) & 63, s = (i >> 9) & 1, t = i >> 10;
        int code = t * 16 + (lane & 15);
        int dim = s * 32 + (lane >> 4) * 8 + j;
        apk[i] = f2bf(cb[code * 64 + dim]);
    } else {
        int code = threadIdx.x;
        float s = 0.f;
        for (int d = 0; d < 64; ++d) { float v = cb[code * 64 + d]; s += v * v; }
        en[code] = s;
    }
}

// ======================= conv1: 3->256 k4 s2, 128->64, LDS-staged =======================
__global__ __launch_bounds__(256) void k_conv1n(const float* __restrict__ x,
                                                const float* __restrict__ wt,   // [48][256] f32
                                                const float* __restrict__ bias,
                                                ushort* __restrict__ o) {       // NHWC64 bf16
    __shared__ float sx[12][132];
    int b = blockIdx.x;                  // 32n * 64h
    int h = b & 63, n = b >> 6;
    int tid = threadIdx.x;
    for (int c = tid; c < 12 * 128; c += 256) {
        int t = c >> 7, wi = c & 127;
        int ci = t >> 2, kh = t & 3;
        int hi = 2 * h - 1 + kh;
        float v = ((unsigned)hi < 128u) ? x[((long)n * 3 + ci) * 16384 + hi * 128 + wi] : 0.f;
        sx[t][wi + 1] = v;
    }
    if (tid < 24) { int t = tid >> 1; sx[t][(tid & 1) ? 129 : 0] = 0.f; }
    int co = tid;
    float wr[48];
#pragma unroll
    for (int k = 0; k < 48; ++k) wr[k] = wt[k * 256 + co];
    float bco = bias[co];
    __syncthreads();
    ushort* op = o + (((long)n * 64 + h) * 64) * 256 + co;
    for (int w = 0; w < 64; ++w) {
        float acc = bco;
#pragma unroll
        for (int t = 0; t < 12; ++t) {
            const float* xr = &sx[t][2 * w];
            acc += xr[0] * wr[t * 4] + xr[1] * wr[t * 4 + 1]
                 + xr[2] * wr[t * 4 + 2] + xr[3] * wr[t * 4 + 3];
        }
        op[w * 256] = f2bf(acc);
    }
}

// ======================= unified MFMA conv (R8 structure, bf16 chain) ===========
// MODE 0: 3x3 pad1 (9 taps), 32x32 NHWC  (RELU_STAGE applies relu on load)
// MODE 1: 1x1
// MODE 2: conv2 4x4 s2 (4 phases x 4 taps), in 64x64 NHWC
// MODE 3: deconv1 per-parity (4 taps), in 32x32 NHWC, out 64x64 NHWC
// Block: 128 threads = 2 waves. Block tile 64co x 128m. Wave tile 64co x 64m.
#define SXE(r, q, c) (((((r) << 2) + (q)) * 34 + (c)) << 3)

template <int MODE, bool HAS_BIAS, bool ADD_RES, bool RELU_STAGE, bool RELU_OUT>
__global__ __launch_bounds__(128, 2) void k_mconv(const ushort* __restrict__ xin,
                                                  const ushort* __restrict__ wpk,
                                                  const float* __restrict__ bias,
                                                  const ushort* __restrict__ res,
                                                  ushort* __restrict__ obf) {
    constexpr int NT = (MODE == 0) ? 9 : ((MODE == 1) ? 1 : 4);
    constexpr int NOUT = (MODE == 2) ? 32 : 8;
    constexpr int NR = (MODE == 1) ? 4 : 6;
    constexpr int NTA = (MODE == 0) ? 1 : NT;

    __shared__ __align__(16) ushort sX[6 * 4 * 34 * 8];   // 13056 B

    int tid = threadIdx.x;
    int lane = tid & 63, wv = tid >> 6;               // 2 waves
    int q = lane >> 4, l15 = lane & 15;
    int b = blockIdx.x;
    int mblk = b & 7, coslab = (b >> 3) & 3;
    int cls = (MODE == 3) ? ((b >> 5) & 3) : 0;
    int n = (MODE == 3) ? (b >> 7) : (b >> 5);
    int h0 = mblk * 4;

    if (tid < 48) {
        int r = tid / 8, rem = tid & 7, qq = rem >> 1, cc = (rem & 1) ? 33 : 0;
        uint4 z; z.x = z.y = z.z = z.w = 0;
        *(uint4*)&sX[SXE(r, qq, cc)] = z;
    }

    int qsel = tid & 3;
    int wst = (tid >> 2) & 31;

    int bbase[4];
#pragma unroll
    for (int bt = 0; bt < 4; ++bt) {
        int mloc = wv * 64 + bt * 16 + l15;           // 0..127
        int ro = mloc >> 5, col = mloc & 31;
        bbase[bt] = SXE(ro + 1, q, col + 1);
    }

    f32x4 acc[4][4];
#pragma unroll
    for (int at = 0; at < 4; ++at)
#pragma unroll
        for (int bt = 0; bt < 4; ++bt) acc[at][bt] = 0.f;

    uint4 sreg[NR];
    auto stage_load = [&](int it2) {
        int cb2 = (MODE == 2) ? (it2 >> 2) : it2;
        int ph2 = (MODE == 2) ? (it2 & 3) : 0;
        int ph_h2 = ph2 >> 1, ph_w2 = ph2 & 1;
#pragma unroll
        for (int r = 0; r < NR; ++r) {
            int rr = (MODE == 1) ? r + 1 : r;
            int hh = h0 + rr - 1;
            bool valid = (unsigned)hh < 32u;
            long off2;
            if (MODE == 2)
                off2 = (((long)n * 64 + 2 * hh + ph_h2) * 64 + (2 * wst + ph_w2)) * 256 + cb2 * 32 + qsel * 8;
            else
                off2 = (((long)n * 32 + hh) * 32 + wst) * 256 + cb2 * 32 + qsel * 8;
            uint4 v;
            if (valid) {
                v = *(const uint4*)(xin + off2);
                if (RELU_STAGE) v = relu4(v);
            } else { v.x = 0; v.y = 0; v.z = 0; v.w = 0; }
            sreg[r] = v;
        }
    };
    stage_load(0);

    for (int it = 0; it < NOUT; ++it) {
        int cb = (MODE == 2) ? (it >> 2) : it;
        int ph = (MODE == 2) ? (it & 3) : 0;
        int ph_h = ph >> 1, ph_w = ph & 1;
        int clsi = (MODE == 2) ? ph : cls;
        const ushort* wb = wpk + ((((long)(clsi * NT)) * 8 + cb) * 256 + coslab * 64 + l15) * 32 + q * 8;

        // A-frag preload (independent of LDS; overlaps the barrier)
        bf16x8 afA[NTA][4];
        if (MODE == 0) {
#pragma unroll
            for (int at = 0; at < 4; ++at) afA[0][at] = *(const bf16x8*)(wb + at * 512);
        } else {
#pragma unroll
            for (int t = 0; t < NT; ++t)
#pragma unroll
                for (int at = 0; at < 4; ++at)
                    afA[t][at] = *(const bf16x8*)(wb + (long)t * 65536 + at * 512);
        }

        __syncthreads();                 // previous taps' LDS reads done
#pragma unroll
        for (int r = 0; r < NR; ++r) {
            int rr = (MODE == 1) ? r + 1 : r;
            *(uint4*)&sX[SXE(rr, qsel, wst + 1)] = sreg[r];
        }
        if (it + 1 < NOUT) stage_load(it + 1);   // prefetch, loads stay in flight
        __syncthreads();                 // staging visible

        if (MODE == 0) {
            bf16x8 afc[4];
#pragma unroll
            for (int at = 0; at < 4; ++at) afc[at] = afA[0][at];
#pragma unroll
            for (int t = 0; t < 9; ++t) {
                bf16x8 afn[4];
                if (t < 8) {
#pragma unroll
                    for (int at = 0; at < 4; ++at)
                        afn[at] = *(const bf16x8*)(wb + (long)(t + 1) * 65536 + at * 512);
                }
                int dy = t / 3 - 1, dx = t % 3 - 1;
                int doff = (dy * 136 + dx) * 8;
                bf16x8 bfr[4];
#pragma unroll
                for (int bt = 0; bt < 4; ++bt) bfr[bt] = *(const bf16x8*)&sX[bbase[bt] + doff];
#pragma unroll
                for (int at = 0; at < 4; ++at)
#pragma unroll
                    for (int bt = 0; bt < 4; ++bt)
                        acc[at][bt] = __builtin_amdgcn_mfma_f32_16x16x32_bf16(afc[at], bfr[bt],
                                                                              acc[at][bt], 0, 0, 0);
                if (t < 8) {
#pragma unroll
                    for (int at = 0; at < 4; ++at) afc[at] = afn[at];
                }
            }
        } else {
#pragma unroll
            for (int t = 0; t < NT; ++t) {
                int dy, dx;
                if (MODE == 1) { dy = 0; dx = 0; }
                else if (MODE == 2) { dy = (t >> 1) - ph_h; dx = (t & 1) - ph_w; }
                else { dy = (cls >> 1) - (t >> 1); dx = (cls & 1) - (t & 1); }
                int doff = (dy * 136 + dx) * 8;
                bf16x8 bfr[4];
#pragma unroll
                for (int bt = 0; bt < 4; ++bt) bfr[bt] = *(const bf16x8*)&sX[bbase[bt] + doff];
#pragma unroll
                for (int at = 0; at < 4; ++at)
#pragma unroll
                    for (int bt = 0; bt < 4; ++bt)
                        acc[at][bt] = __builtin_amdgcn_mfma_f32_16x16x32_bf16(afA[t][at], bfr[bt],
                                                                              acc[at][bt], 0, 0, 0);
            }
        }
    }

    // ---- epilogue (all-bf16) ----
    int co_base = coslab * 64;
#pragma unroll
    for (int at = 0; at < 4; ++at) {
        int co_t = co_base + at * 16 + q * 4;
        float bv[4] = {0.f, 0.f, 0.f, 0.f};
        if (HAS_BIAS) {
            float4 b4 = *(const float4*)(bias + co_t);
            bv[0] = b4.x; bv[1] = b4.y; bv[2] = b4.z; bv[3] = b4.w;
        }
#pragma unroll
        for (int bt = 0; bt < 4; ++bt) {
            int m = mblk * 128 + wv * 64 + bt * 16 + l15;
            long oaddr;
            if (MODE == 3) {
                int oy = m >> 5, ox = m & 31;
                int py = cls >> 1, px = cls & 1;
                oaddr = (((long)n * 64 + 2 * oy + py) * 64 + 2 * ox + px) * 256 + co_t;
            } else {
                oaddr = ((long)n * 1024 + m) * 256 + co_t;
            }
            float v[4];
#pragma unroll
            for (int r = 0; r < 4; ++r) v[r] = acc[at][bt][r] + bv[r];
            if (ADD_RES) {
                uint2 rr = *(const uint2*)(res + oaddr);
                v[0] += bfl(rr.x); v[1] += bfh(rr.x);
                v[2] += bfl(rr.y); v[3] += bfh(rr.y);
            }
            if (RELU_OUT) {
#pragma unroll
                for (int r = 0; r < 4; ++r) v[r] = fmaxf(v[r], 0.f);
            }
            uint2 pk;
            pk.x = (unsigned)f2bf(v[0]) | ((unsigned)f2bf(v[1]) << 16);
            pk.y = (unsigned)f2bf(v[2]) | ((unsigned)f2bf(v[3]) << 16);
            *(uint2*)(obf + oaddr) = pk;
        }
    }
}

// ======================= VQ via MFMA (bf16 out only) =======================
__global__ __launch_bounds__(256) void k_vq2(const ushort* __restrict__ zb,
                                             const ushort* __restrict__ apk,  // [16][2][64][8]
                                             const float* __restrict__ en,    // [256]
                                             const float* __restrict__ cbf,   // [256][64] fp32
                                             ushort* __restrict__ vqb,        // bf16 NHWC (no relu)
                                             float* __restrict__ loss) {
    __shared__ int sIdx[64];
    __shared__ float sLoss[64];
    int tid = threadIdx.x, lane = tid & 63, wv = tid >> 6;
    int q = lane >> 4, l15 = lane & 15;
    int r0 = blockIdx.x * 64;
    int R = r0 + wv * 16;

    const ushort* zp = zb + ((long)(R + l15)) * 64 + q * 8;
    bf16x8 b0 = *(const bf16x8*)zp;
    bf16x8 b1 = *(const bf16x8*)(zp + 32);

    float z2 = 0.f;
    {
        const unsigned* u0 = (const unsigned*)&b0;
        const unsigned* u1 = (const unsigned*)&b1;
#pragma unroll
        for (int i = 0; i < 4; ++i) {
            float a = bfl(u0[i]), bb = bfh(u0[i]);
            float c = bfl(u1[i]), d = bfh(u1[i]);
            z2 += a * a + bb * bb + c * c + d * d;
        }
    }

    float best = 3.4e38f;
    int bidx = 0;
#pragma unroll
    for (int t = 0; t < 16; ++t) {
        bf16x8 a0 = *(const bf16x8*)(apk + ((t * 2 + 0) * 64 + lane) * 8);
        bf16x8 a1 = *(const bf16x8*)(apk + ((t * 2 + 1) * 64 + lane) * 8);
        f32x4 acc = {0.f, 0.f, 0.f, 0.f};
        acc = __builtin_amdgcn_mfma_f32_16x16x32_bf16(a0, b0, acc, 0, 0, 0);
        acc = __builtin_amdgcn_mfma_f32_16x16x32_bf16(a1, b1, acc, 0, 0, 0);
        float4 e4 = *(const float4*)(en + t * 16 + q * 4);
        float sc[4] = {e4.x - 2.f * acc[0], e4.y - 2.f * acc[1],
                       e4.z - 2.f * acc[2], e4.w - 2.f * acc[3]};
#pragma unroll
        for (int r = 0; r < 4; ++r) {
            int code = t * 16 + q * 4 + r;
            if (sc[r] < best) { best = sc[r]; bidx = code; }
        }
    }
#pragma unroll
    for (int m = 16; m <= 32; m <<= 1) {
        float ob = __shfl_xor(best, m);
        int oi = __shfl_xor(bidx, m);
        if (ob < best || (ob == best && oi < bidx)) { best = ob; bidx = oi; }
        z2 += __shfl_xor(z2, m);
    }
    if (q == 0) {
        sIdx[wv * 16 + l15] = bidx;
        sLoss[wv * 16 + l15] = best + z2;
    }
    __syncthreads();

    if (wv == 0) {
        float l = sLoss[lane];
#pragma unroll
        for (int m = 1; m < 64; m <<= 1) l += __shfl_xor(l, m);
        if (lane == 0) atomicAdd(loss, l * (1.25f / 8388608.f));
    }

    unsigned* vb = (unsigned*)(vqb + (long)r0 * 64);
#pragma unroll
    for (int k = 0; k < 8; ++k) {
        int i = k * 256 + tid;           // 0..2047 uints
        int rl = i >> 5, jp = i & 31;
        int idx = sIdx[rl];
        float v0 = cbf[idx * 64 + 2 * jp];
        float v1 = cbf[idx * 64 + 2 * jp + 1];
        vb[i] = (unsigned)f2bf(v0) | ((unsigned)f2bf(v1) << 16);
    }
}

// ======================= deconv2 via MFMA (R8 version) =======================
#define SDE(r, q, c) (((((r) << 2) + (q)) * 66 + (c)) << 3)

__global__ __launch_bounds__(256, 2) void k_deconv2m(const ushort* __restrict__ xin,
                                                     const ushort* __restrict__ wpk, // [9][8][16][32]
                                                     const float* __restrict__ bias,
                                                     float* __restrict__ o) {
    __shared__ __align__(16) ushort sX[6 * 4 * 66 * 8];   // 25344 B

    int tid = threadIdx.x, lane = tid & 63, wv = tid >> 6;
    int q = lane >> 4, l15 = lane & 15;
    int b = blockIdx.x;                   // 32n * 16mt = 512
    int mt = b & 15, n = b >> 4;
    int h0 = mt * 4;

    if (tid < 48) {
        int r = tid / 8, rem = tid & 7, qq = rem >> 1, cc = (rem & 1) ? 65 : 0;
        uint4 z; z.x = z.y = z.z = z.w = 0;
        *(uint4*)&sX[SDE(r, qq, cc)] = z;
    }

    int qsel = tid & 3, wst = (tid >> 2) & 63;

    int bbase[4];
#pragma unroll
    for (int bt = 0; bt < 4; ++bt) {
        int mloc = wv * 64 + bt * 16 + l15;       // 0..255
        int ro = mloc >> 6, col = mloc & 63;
        bbase[bt] = SDE(ro + 1, q, col + 1);
    }

    f32x4 acc[4];
#pragma unroll
    for (int bt = 0; bt < 4; ++bt) acc[bt] = 0.f;

    uint4 sreg[6];
    auto stage_load = [&](int cb2) {
#pragma unroll
        for (int r = 0; r < 6; ++r) {
            int hh = h0 + r - 1;
            uint4 v;
            if ((unsigned)hh < 64u)
                v = *(const uint4*)(xin + (((long)n * 64 + hh) * 64 + wst) * 256 + cb2 * 32 + qsel * 8);
            else { v.x = 0; v.y = 0; v.z = 0; v.w = 0; }
            sreg[r] = v;
        }
    };
    stage_load(0);

    for (int cb = 0; cb < 8; ++cb) {
        bf16x8 afA[9];
#pragma unroll
        for (int t = 0; t < 9; ++t)
            afA[t] = *(const bf16x8*)(wpk + (((t * 8 + cb) * 16 + l15) * 32 + q * 8));

        __syncthreads();
#pragma unroll
        for (int r = 0; r < 6; ++r)
            *(uint4*)&sX[SDE(r, qsel, wst + 1)] = sreg[r];
        if (cb < 7) stage_load(cb + 1);
        __syncthreads();

#pragma unroll
        for (int t = 0; t < 9; ++t) {
            int dy = t / 3 - 1, dx = t % 3 - 1;
            int doff = (dy * 4 * 66 + dx) * 8;
#pragma unroll
            for (int bt = 0; bt < 4; ++bt) {
                bf16x8 bf = *(const bf16x8*)&sX[bbase[bt] + doff];
                acc[bt] = __builtin_amdgcn_mfma_f32_16x16x32_bf16(afA[t], bf, acc[bt], 0, 0, 0);
            }
        }
    }

    if (q < 3) {
#pragma unroll
        for (int bt = 0; bt < 4; ++bt) {
            int mloc = wv * 64 + bt * 16 + l15;
            int u = h0 + (mloc >> 6), v = mloc & 63;
#pragma unroll
            for (int r = 0; r < 4; ++r) {
                int oc = q * 4 + r;
                int cls = oc / 3, cs = oc - cls * 3;
                int py = cls >> 1, px = cls & 1;
                o[(((long)n * 3 + cs) * 128 + 2 * u + py) * 128 + 2 * v + px] =
                    tanhf(acc[bt][r] + bias[cs]);
            }
        }
    }
}

// ======================= launcher =======================
extern "C" void kernel_launch(void* const* d_in, const int* in_sizes, int n_in,
                              void* d_out, int out_size, void* d_ws, size_t ws_size,
                              hipStream_t stream) {
    (void)in_sizes; (void)n_in; (void)out_size; (void)ws_size;
    const float* x        = (const float*)d_in[0];
    const float* enc_w1   = (const float*)d_in[1];
    const float* enc_b1   = (const float*)d_in[2];
    const float* enc_w2   = (const float*)d_in[3];
    const float* enc_b2   = (const float*)d_in[4];
    const float* er1_w3   = (const float*)d_in[5];
    const float* er1_w1   = (const float*)d_in[6];
    const float* er2_w3   = (const float*)d_in[7];
    const float* er2_w1   = (const float*)d_in[8];
    const float* codebook = (const float*)d_in[9];
    const float* dr1_w3   = (const float*)d_in[10];
    const float* dr1_w1   = (const float*)d_in[11];
    const float* dr2_w3   = (const float*)d_in[12];
    const float* dr2_w1   = (const float*)d_in[13];
    const float* dt1_w    = (const float*)d_in[14];
    const float* dt1_b    = (const float*)d_in[15];
    const float* dt2_w    = (const float*)d_in[16];
    const float* dt2_b    = (const float*)d_in[17];

    float* recon = (float*)d_out;
    float* loss  = recon + 1572864;

    char* ws = (char*)d_ws;
    size_t off = 0;
    auto alloc = [&](size_t bytes) { char* p = ws + off; off += (bytes + 255) & ~(size_t)255; return p; };
    ushort* N64  = (ushort*)alloc(67108864);   // [32,64,64,256] bf16
    ushort* X0   = (ushort*)alloc(16777216);   // bf16 NHWC 32x32 tensors
    ushort* X1   = (ushort*)alloc(16777216);
    ushort* X2   = (ushort*)alloc(16777216);
    ushort* X3   = (ushort*)alloc(16777216);
    ushort* X4   = (ushort*)alloc(16777216);
    ushort* wpk_c2   = (ushort*)alloc(2097152);
    ushort* wpk_dc1  = (ushort*)alloc(2097152);
    ushort* wpk_er13 = (ushort*)alloc(1179648);
    ushort* wpk_er23 = (ushort*)alloc(1179648);
    ushort* wpk_dr13 = (ushort*)alloc(1179648);
    ushort* wpk_dr23 = (ushort*)alloc(1179648);
    ushort* wpk_er11 = (ushort*)alloc(131072);
    ushort* wpk_er21 = (ushort*)alloc(131072);
    ushort* wpk_dr11 = (ushort*)alloc(131072);
    ushort* wpk_dr21 = (ushort*)alloc(131072);
    float*  wt_c1    = (float*)alloc(49152);
    ushort* w2pk     = (ushort*)alloc(73728);
    ushort* apk      = (ushort*)alloc(32768);
    float*  en       = (float*)alloc(1024);

    hipMemsetAsync(loss, 0, sizeof(float), stream);

    // weight packing
    k_pack_c1f<<<48, 256, 0, stream>>>(enc_w1, wt_c1);
    k_pack_c2dc1<<<8192, 256, 0, stream>>>(enc_w2, dt1_w, wpk_c2, wpk_dc1);
    k_pack_c3x4<<<9216, 256, 0, stream>>>(er1_w3, er2_w3, dr1_w3, dr2_w3,
                                          wpk_er13, wpk_er23, wpk_dr13, wpk_dr23);
    k_pack_c1x1x4<<<1024, 256, 0, stream>>>(er1_w1, er2_w1, dr1_w1, dr2_w1,
                                            wpk_er11, wpk_er21, wpk_dr11, wpk_dr21);
    k_pack_dc2m<<<144, 256, 0, stream>>>(dt2_w, w2pk);
    k_pack_vq<<<65, 256, 0, stream>>>(codebook, apk, en);

    // encoder
    k_conv1n<<<2048, 256, 0, stream>>>(x, wt_c1, enc_b1, N64);
    // conv2: N64 -> X0 (z2, no relu)
    k_mconv<2, true, false, false, false><<<1024, 128, 0, stream>>>(N64, wpk_c2, enc_b2, nullptr, X0);
    // er1: 3x3(relu-stage) X0 -> X1(relu'd) ; 1x1 X1 + res X0 -> X2
    k_mconv<0, false, false, true, true><<<1024, 128, 0, stream>>>(X0, wpk_er13, nullptr, nullptr, X1);
    k_mconv<1, false, true, false, false><<<1024, 128, 0, stream>>>(X1, wpk_er11, nullptr, X0, X2);
    // er2: X2 -> X1 ; X1 + res X2 -> X3 (z, VQ input)
    k_mconv<0, false, false, true, true><<<1024, 128, 0, stream>>>(X2, wpk_er23, nullptr, nullptr, X1);
    k_mconv<1, false, true, false, false><<<1024, 128, 0, stream>>>(X1, wpk_er21, nullptr, X2, X3);
    // VQ: X3 -> X4 (vq, no relu) + loss
    k_vq2<<<2048, 256, 0, stream>>>(X3, apk, en, codebook, X4, loss);
    // dr1: X4 -> X1 ; X1 + res X4 -> X0
    k_mconv<0, false, false, true, true><<<1024, 128, 0, stream>>>(X4, wpk_dr13, nullptr, nullptr, X1);
    k_mconv<1, false, true, false, false><<<1024, 128, 0, stream>>>(X1, wpk_dr11, nullptr, X4, X0);
    // dr2: X0 -> X1 ; X1 + res X0 -> X2
    k_mconv<0, false, false, true, true><<<1024, 128, 0, stream>>>(X0, wpk_dr23, nullptr, nullptr, X1);
    k_mconv<1, false, true, false, false><<<1024, 128, 0, stream>>>(X1, wpk_dr21, nullptr, X0, X2);
    // deconv1: X2 -> N64
    k_mconv<3, true, false, false, false><<<4096, 128, 0, stream>>>(X2, wpk_dc1, dt1_b, nullptr, N64);
    // deconv2 + tanh
    k_deconv2m<<<512, 256, 0, stream>>>(N64, w2pk, dt2_b, recon);
}